// Round 15
// baseline (102.772 us; speedup 1.0000x reference)
//
#include <hip/hip_runtime.h>

// BinaryConv2dSkip1x1 forward, MI355X — full-MFMA, vectorized-halo version.
// out = RPReLU( conv3x3( sign(x+mb), sf*sign(w), pad=1 ) ) + conv1x1(x, skip_w) + skip_b
//
// Binary conv: sign bits expanded to +/-1 int8 planes in LDS (halo/OOB stored 0
// => exact zero padding), computed with mfma_i32_16x16x64_i8.
// Skip 1x1 conv: bf16 mfma_f32_16x16x32_bf16 over K=64.
// Round-15: base = r9 (98us best). Halo row vectorization: top/bottom halo rows
// (32 px x 64 ch each) are loaded with the SAME float4 pattern as the interior
// (wave 2 -> top row, wave 3 -> bottom row; 8 float4/lane + shfl OR-tree),
// instead of 2-threads-per-px scalar channel gathers. Only the 20 column/corner
// halo px keep the scalar path. Scatter transactions per block: 5376 -> ~1280.
// (r9-r14 evidence: all pipes <40%, eff BW pinned 2.5-3 TB/s => scatter-bound.)

#define HW (256*256)

typedef __bf16 bf16x8 __attribute__((ext_vector_type(8)));
typedef float  f32x4  __attribute__((ext_vector_type(4)));
typedef int    i32x4  __attribute__((ext_vector_type(4)));

__device__ __forceinline__ void lds_fence() {
    asm volatile("s_waitcnt lgkmcnt(0)" ::: "memory");
}

// expand 4 sign bits -> 4 i8 bytes (+1 for bit=0, -1 for bit=1)
__device__ __forceinline__ int expand4(unsigned int nib) {
    unsigned int spread = (nib * 0x00204081u) & 0x01010101u;  // bit i -> byte i LSB
    return (int)(0x01010101u ^ (spread * 0xFEu));             // 0x01 or 0xFF per byte
}

// ---------------- prep kernel: one block, 576 threads (o = tid/9, t = tid%9) ----------
__global__ void bq_prep_kernel(const float* __restrict__ weight,   // [64][64][3][3]
                               const float* __restrict__ pr_bias0,
                               const float* __restrict__ prelu_w,
                               const float* __restrict__ pr_bias1,
                               const float* __restrict__ skip_b,
                               const float* __restrict__ skipw,    // [64][64]
                               unsigned short* __restrict__ abits, // [4rt][64 lane][10] u16
                               unsigned short* __restrict__ swfrag,// [4rt][2p][64 lane][8] bf16
                               float* __restrict__ consg) {        // [64][4]
    __shared__ float sabs_l[576];
    const int tid = threadIdx.x;
    const int o = tid / 9, t = tid % 9;
    const int m = o & 15, rt = o >> 4;
    unsigned short bg[4] = {0, 0, 0, 0};
    float sabs = 0.f;
    for (int ch = 0; ch < 64; ++ch) {
        float wv = weight[(o*64 + ch)*9 + t];
        sabs += fabsf(wv);
        if (wv < 0.f) bg[ch >> 4] |= (unsigned short)(1u << (ch & 15));
    }
    // lane l = m + 16*g holds A[m][k], k = g*16 + j; bit j of abits word = sign
    #pragma unroll
    for (int g = 0; g < 4; ++g)
        abits[(rt*64 + m + 16*g)*10 + t] = bg[g];
    sabs_l[tid] = sabs;
    __syncthreads();
    if (t == 0) {
        float s = 0.f;
        #pragma unroll
        for (int k = 0; k < 9; ++k) s += sabs_l[o*9 + k];
        float sf = s / 576.f;
        consg[o*4 + 0] = sf;
        consg[o*4 + 1] = pr_bias0[o];
        consg[o*4 + 2] = prelu_w[o];
        consg[o*4 + 3] = pr_bias1[o] + skip_b[o];
    }
    if (t == 1) {
        for (int p = 0; p < 2; ++p)
            for (int gg = 0; gg < 4; ++gg)
                for (int i = 0; i < 8; ++i) {
                    float wv = skipw[o*64 + p*32 + gg*8 + i];
                    swfrag[((rt*2 + p)*64 + (m + 16*gg))*8 + i] =
                        __builtin_bit_cast(unsigned short, (__bf16)wv);
                }
    }
}

// ---------------- main kernel: tile 32 px x 8 rows, 512 threads (wave = one row) ------
__global__ __launch_bounds__(512, 2)
void bq_main_kernel(const float* __restrict__ x,        // [8][64][256][256]
                    const float* __restrict__ mb,       // [64]
                    const unsigned short* __restrict__ abits_g,
                    const unsigned short* __restrict__ swfrag,
                    const float* __restrict__ consg,
                    float* __restrict__ out) {
    __shared__ __align__(16) char planes[10*4*34*16];      // 21760 B; first 16 KB double as
                                                           // per-wave bf16 exchange (2 KB/wave)
    __shared__ __align__(16) unsigned short Abits[4*64*10];// 5120 B
    __shared__ __align__(16) float cons[64*4];             // 1024 B  => 27904 B total

    const int tid = threadIdx.x;
    const int l = tid & 63, w = tid >> 6;
    const int pxg = l & 7,  chg = l >> 3;   // 4-px group / 8-ch group
    const int lg = l >> 4,  lr = l & 15;

    // XCD swizzle: one batch image per XCD (id&7 = XCD under round-robin dispatch).
    const int id  = blockIdx.x;                 // 0..2047
    const int vid = (id & 7)*256 + (id >> 3);
    const int byp = vid & 31;                   // 0..31
    const int rest = vid >> 5;                  // 0..63
    const int bxp = rest & 7;                   // 0..7
    const int b   = rest >> 3;                  // 0..7

    const int h0 = byp*8 + w, px0 = bxp*32;
    const float* xb = x + (size_t)b * 64 * HW;

    for (int i = tid; i < 1280; i += 512)
        ((unsigned int*)Abits)[i] = ((const unsigned int*)abits_g)[i];
    if (tid < 64) ((f32x4*)cons)[tid] = ((const f32x4*)consg)[tid];

    // ---- Column/corner halo (scalar path): cols px0-1 & px0+32, rows byp*8-1..+8.
    // 20 px x 2 ch-halves = 40 jobs on threads 256..295 (lanes 0..39 of wave 4).
    int hr_ = 0, hc_ = 0, hhh = 0;
    bool hinb = false;
    unsigned int hbb0 = 0, hbb1 = 0;
    const bool lrth = (tid >= 256 && tid < 296);
    if (lrth) {
        const int j = tid - 256;          // 0..39
        const int pxi = j >> 1;           // 0..19
        hhh = j & 1;
        const int side = (pxi >= 10) ? 1 : 0;
        const int r = pxi - side*10;      // 0..9
        hr_ = r;
        hc_ = side ? 33 : 0;
        const int hg = byp*8 + r - 1;
        const int wg = side ? (px0 + 32) : (px0 - 1);
        hinb = (hg >= 0 && hg < 256 && wg >= 0 && wg < 256);
        if (hinb) {
            const int po = hg*256 + wg;
            #pragma unroll
            for (int j16 = 0; j16 < 16; ++j16) {
                const int c0 = hhh*16 + j16;
                const int c1 = 32 + hhh*16 + j16;
                hbb0 |= (__float_as_uint(xb[(size_t)c0*HW + po] + mb[c0]) >> 31) << j16;
                hbb1 |= (__float_as_uint(xb[(size_t)c1*HW + po] + mb[c1]) >> 31) << j16;
            }
        }
    }

    // ---- Interior loads: lane covers 4 px (pxg*4..+3) x 8 ch (chg*8..+7).
    const f32x4* xrow = (const f32x4*)(xb + (size_t)(chg*8)*HW + h0*256 + px0 + pxg*4);
    f32x4 v[8];
    #pragma unroll
    for (int i = 0; i < 8; ++i) v[i] = xrow[(size_t)i*(HW/4)];
    const f32x4 m0 = *(const f32x4*)&mb[chg*8];
    const f32x4 m1 = *(const f32x4*)&mb[chg*8 + 4];

    // ---- Halo ROW loads (vectorized, same pattern): w==2 -> top, w==3 -> bottom.
    const bool ishw = (w == 2) || (w == 3);
    const int hrow = (w == 2) ? (byp*8 - 1) : (byp*8 + 8);
    const bool hrow_inb = ishw && (hrow >= 0) && (hrow < 256);
    f32x4 hv[8];
    if (hrow_inb) {
        const f32x4* hxrow = (const f32x4*)(xb + (size_t)(chg*8)*HW + hrow*256 + px0 + pxg*4);
        #pragma unroll
        for (int i = 0; i < 8; ++i) hv[i] = hxrow[(size_t)i*(HW/4)];
    }

    // ---- Interior pack: sign words + bf16.
    unsigned long long sb0, sb1, sb2, sb3;
    bf16x8 pk[4];
    {
        unsigned int by[4];
        #pragma unroll
        for (int e = 0; e < 4; ++e) {
            unsigned int bb = 0;
            #pragma unroll
            for (int i = 0; i < 8; ++i) {
                float xv = v[i][e];
                float mm = (i < 4) ? m0[i] : m1[i-4];
                bb |= (__float_as_uint(xv + mm) >> 31) << i;
                pk[e][i] = (__bf16)xv;
            }
            by[e] = bb;
        }
        const int sh = chg*8;
        sb0 = ((unsigned long long)by[0]) << sh;
        sb1 = ((unsigned long long)by[1]) << sh;
        sb2 = ((unsigned long long)by[2]) << sh;
        sb3 = ((unsigned long long)by[3]) << sh;
    }
    #pragma unroll
    for (int m = 8; m <= 32; m <<= 1) {
        sb0 |= __shfl_xor(sb0, m);
        sb1 |= __shfl_xor(sb1, m);
        sb2 |= __shfl_xor(sb2, m);
        sb3 |= __shfl_xor(sb3, m);
    }

    // ---- Halo row pack (waves 2/3 only; wave-uniform branch).
    unsigned long long hsb0 = 0, hsb1 = 0, hsb2 = 0, hsb3 = 0;
    if (hrow_inb) {
        unsigned int hby[4];
        #pragma unroll
        for (int e = 0; e < 4; ++e) {
            unsigned int bb = 0;
            #pragma unroll
            for (int i = 0; i < 8; ++i) {
                float mm = (i < 4) ? m0[i] : m1[i-4];
                bb |= (__float_as_uint(hv[i][e] + mm) >> 31) << i;
            }
            hby[e] = bb;
        }
        const int sh = chg*8;
        hsb0 = ((unsigned long long)hby[0]) << sh;
        hsb1 = ((unsigned long long)hby[1]) << sh;
        hsb2 = ((unsigned long long)hby[2]) << sh;
        hsb3 = ((unsigned long long)hby[3]) << sh;
        #pragma unroll
        for (int m = 8; m <= 32; m <<= 1) {
            hsb0 |= __shfl_xor(hsb0, m);
            hsb1 |= __shfl_xor(hsb1, m);
            hsb2 |= __shfl_xor(hsb2, m);
            hsb3 |= __shfl_xor(hsb3, m);
        }
    }

    // ---- Skip-conv MFMAs in two 16-px passes through per-wave LDS exchange.
    // xsl layout: [8 slot][16 px][8] u16 (slot = ch octet); overlays planes.
    f32x4 skacc[4][2];
    #pragma unroll
    for (int rt = 0; rt < 4; ++rt)
        #pragma unroll
        for (int g = 0; g < 2; ++g) skacc[rt][g] = (f32x4){0.f, 0.f, 0.f, 0.f};

    unsigned short* xsl = (unsigned short*)((char*)planes + w*2048);
    #pragma unroll
    for (int g = 0; g < 2; ++g) {
        if ((pxg >> 2) == g) {
            const int px16 = (pxg & 3)*4;
            *(bf16x8*)&xsl[(chg*16 + px16 + 0)*8] = pk[0];
            *(bf16x8*)&xsl[(chg*16 + px16 + 1)*8] = pk[1];
            *(bf16x8*)&xsl[(chg*16 + px16 + 2)*8] = pk[2];
            *(bf16x8*)&xsl[(chg*16 + px16 + 3)*8] = pk[3];
        }
        lds_fence();   // wave-synchronous: writes visible before reads
        #pragma unroll
        for (int p = 0; p < 2; ++p) {
            // B-frag: slot p*4 + lg (ch p*32 + lg*8 ..+7), px = lr (actual px g*16+lr)
            bf16x8 bx = *(const bf16x8*)&xsl[((p*4 + lg)*16 + lr)*8];
            #pragma unroll
            for (int rt = 0; rt < 4; ++rt) {
                bf16x8 sa = *(const bf16x8*)&swfrag[((rt*2 + p)*64 + l)*8];
                skacc[rt][g] = __builtin_amdgcn_mfma_f32_16x16x32_bf16(
                    sa, bx, skacc[rt][g], 0, 0, 0);
            }
        }
        lds_fence();   // reads done before next pass overwrites
    }
    __syncthreads();   // all waves done with the exchange overlay

    // ---- Interior sign planes: lane writes px = pxg*4 + (chg&3), 2 slots.
    {
        const int e = chg & 3;
        unsigned long long mysb = (e == 0) ? sb0 : (e == 1) ? sb1 : (e == 2) ? sb2 : sb3;
        const int px = pxg*4 + e;
        const int sbase = (chg >> 2)*2;
        #pragma unroll
        for (int sp = 0; sp < 2; ++sp) {
            const int s = sbase + sp;
            unsigned int slice = (unsigned int)(mysb >> (s*16)) & 0xffffu;
            i32x4 dw;
            dw[0] = expand4(slice & 15);
            dw[1] = expand4((slice >> 4) & 15);
            dw[2] = expand4((slice >> 8) & 15);
            dw[3] = expand4((slice >> 12) & 15);
            *(i32x4*)&planes[(((w + 1)*4 + s)*34 + px + 1)*16] = dw;
        }
    }

    // ---- Halo ROW plane writes (waves 2/3): plane row 0 (top) / 9 (bottom),
    // px cols 1..32. OOB rows write zero bytes (exact zero padding).
    if (ishw) {
        const int prow = (w == 2) ? 0 : 9;
        const int e = chg & 3;
        unsigned long long mysb = (e == 0) ? hsb0 : (e == 1) ? hsb1
                                 : (e == 2) ? hsb2 : hsb3;
        const int px = pxg*4 + e;
        const int sbase = (chg >> 2)*2;
        #pragma unroll
        for (int sp = 0; sp < 2; ++sp) {
            const int s = sbase + sp;
            i32x4 dw = (i32x4){0, 0, 0, 0};
            if (hrow_inb) {
                unsigned int slice = (unsigned int)(mysb >> (s*16)) & 0xffffu;
                dw[0] = expand4(slice & 15);
                dw[1] = expand4((slice >> 4) & 15);
                dw[2] = expand4((slice >> 8) & 15);
                dw[3] = expand4((slice >> 12) & 15);
            }
            *(i32x4*)&planes[((prow*4 + s)*34 + px + 1)*16] = dw;
        }
    }

    // ---- Column/corner halo plane writes (threads 256..295).
    if (lrth) {
        #pragma unroll
        for (int p = 0; p < 2; ++p) {
            i32x4 dw = (i32x4){0, 0, 0, 0};
            if (hinb) {
                const unsigned int bb = p ? hbb1 : hbb0;
                dw[0] = expand4(bb & 15);
                dw[1] = expand4((bb >> 4) & 15);
                dw[2] = expand4((bb >> 8) & 15);
                dw[3] = expand4((bb >> 12) & 15);
            }
            *(i32x4*)&planes[((hr_*4 + (hhh + 2*p))*34 + hc_)*16] = dw;
        }
    }
    __syncthreads();

    // ---- Phase C: binary conv via i8 MFMA; A expanded from packed bits per tap.
    const int prow_base = ((w*4 + lg)*34 + lr)*16;
    float* outp = out + (size_t)b*64*HW + h0*256 + px0;

    #pragma unroll
    for (int rt = 0; rt < 4; ++rt) {
        // this lane's packed A row: 5 dwords, stride 20 B (bank-conflict-free)
        const unsigned int* arow = (const unsigned int*)&Abits[(rt*64 + l)*10];
        unsigned int ad[5];
        #pragma unroll
        for (int k = 0; k < 5; ++k) ad[k] = arow[k];

        i32x4 bacc0 = (i32x4){0,0,0,0}, bacc1 = (i32x4){0,0,0,0};
        #pragma unroll
        for (int t = 0; t < 9; ++t) {
            const int dr = t / 3, dc = t % 3;
            const unsigned int tb = (ad[t >> 1] >> ((t & 1)*16)) & 0xffffu;
            i32x4 a;
            a[0] = expand4(tb & 15);
            a[1] = expand4((tb >> 4) & 15);
            a[2] = expand4((tb >> 8) & 15);
            a[3] = expand4((tb >> 12) & 15);
            i32x4 b0 = *(const i32x4*)&planes[prow_base + dr*(4*34*16) + dc*16];
            i32x4 b1 = *(const i32x4*)&planes[prow_base + dr*(4*34*16) + dc*16 + 256];
            bacc0 = __builtin_amdgcn_mfma_i32_16x16x64_i8(a, b0, bacc0, 0, 0, 0);
            bacc1 = __builtin_amdgcn_mfma_i32_16x16x64_i8(a, b1, bacc1, 0, 0, 0);
        }
        #pragma unroll
        for (int qi = 0; qi < 4; ++qi) {
            const int o = rt*16 + lg*4 + qi;
            f32x4 c4 = *(const f32x4*)&cons[o*4];   // (sf, pb0, aP, pb1+skip_b)
            {
                float tv = fmaf(c4[0], (float)bacc0[qi], c4[1]);
                tv = fmaxf(tv, 0.f) + c4[2]*fminf(tv, 0.f);
                outp[(size_t)o*HW + lr] = tv + c4[3] + skacc[rt][0][qi];
            }
            {
                float tv = fmaf(c4[0], (float)bacc1[qi], c4[1]);
                tv = fmaxf(tv, 0.f) + c4[2]*fminf(tv, 0.f);
                outp[(size_t)o*HW + 16 + lr] = tv + c4[3] + skacc[rt][1][qi];
            }
        }
    }
}

extern "C" void kernel_launch(void* const* d_in, const int* in_sizes, int n_in,
                              void* d_out, int out_size, void* d_ws, size_t ws_size,
                              hipStream_t stream) {
    const float* x      = (const float*)d_in[0];
    const float* mb     = (const float*)d_in[1];
    const float* weight = (const float*)d_in[2];
    const float* pb0    = (const float*)d_in[3];
    const float* pw     = (const float*)d_in[4];
    const float* pb1    = (const float*)d_in[5];
    const float* skw    = (const float*)d_in[6];
    const float* skb    = (const float*)d_in[7];
    float* out = (float*)d_out;

    char* ws = (char*)d_ws;
    unsigned short* abits  = (unsigned short*)ws;              // 5120 B
    unsigned short* swfrag = (unsigned short*)(ws + 5120);     // 8192 B
    float*          consg  = (float*)(ws + 13312);             // 1024 B (total 14336)

    hipLaunchKernelGGL(bq_prep_kernel, dim3(1), dim3(576), 0, stream,
                       weight, pb0, pw, pb1, skb, skw, abits, swfrag, consg);
    hipLaunchKernelGGL(bq_main_kernel, dim3(2048), dim3(512), 0, stream,
                       x, mb, abits, swfrag, consg, out);
}

// Round 16
// 93.198 us; speedup vs baseline: 1.1027x; 1.1027x over previous
//
#include <hip/hip_runtime.h>

// BinaryConv2dSkip1x1 forward, MI355X — full-MFMA, small-block high-concurrency.
// out = RPReLU( conv3x3( sign(x+mb), sf*sign(w), pad=1 ) ) + conv1x1(x, skip_w) + skip_b
//
// Binary conv: sign bits expanded to +/-1 int8 planes in LDS (halo/OOB stored 0
// => exact zero padding), computed with mfma_i32_16x16x64_i8.
// Skip 1x1 conv: bf16 mfma_f32_16x16x32_bf16 over K=64.
// Round-16: 256-thread blocks (4 waves), 32x4 tiles, grid 4096. r9-r15 all land
// 98-120us with every pipe <40%: phase-locked 512-thread blocks (2-3/CU) convoy
// (loads burst together, then memory idles during compute). 8 small blocks/CU
// (19.2 KB LDS, VGPR<=64) desynchronize naturally so one block's phase-A loads
// overlap another's phase-C MFMAs. Per-wave work unchanged from r9 (98us best);
// r13's pipelining failure was the VGPR 84->128 quantization cliff, not overlap.

#define HW (256*256)

typedef __bf16 bf16x8 __attribute__((ext_vector_type(8)));
typedef float  f32x4  __attribute__((ext_vector_type(4)));
typedef int    i32x4  __attribute__((ext_vector_type(4)));

__device__ __forceinline__ void lds_fence() {
    asm volatile("s_waitcnt lgkmcnt(0)" ::: "memory");
}

// expand 4 sign bits -> 4 i8 bytes (+1 for bit=0, -1 for bit=1)
__device__ __forceinline__ int expand4(unsigned int nib) {
    unsigned int spread = (nib * 0x00204081u) & 0x01010101u;  // bit i -> byte i LSB
    return (int)(0x01010101u ^ (spread * 0xFEu));             // 0x01 or 0xFF per byte
}

// ---------------- prep kernel: one block, 576 threads (o = tid/9, t = tid%9) ----------
__global__ void bq_prep_kernel(const float* __restrict__ weight,   // [64][64][3][3]
                               const float* __restrict__ pr_bias0,
                               const float* __restrict__ prelu_w,
                               const float* __restrict__ pr_bias1,
                               const float* __restrict__ skip_b,
                               const float* __restrict__ skipw,    // [64][64]
                               unsigned short* __restrict__ abits, // [4rt][64 lane][10] u16
                               unsigned short* __restrict__ swfrag,// [4rt][2p][64 lane][8] bf16
                               float* __restrict__ consg) {        // [64][4]
    __shared__ float sabs_l[576];
    const int tid = threadIdx.x;
    const int o = tid / 9, t = tid % 9;
    const int m = o & 15, rt = o >> 4;
    unsigned short bg[4] = {0, 0, 0, 0};
    float sabs = 0.f;
    for (int ch = 0; ch < 64; ++ch) {
        float wv = weight[(o*64 + ch)*9 + t];
        sabs += fabsf(wv);
        if (wv < 0.f) bg[ch >> 4] |= (unsigned short)(1u << (ch & 15));
    }
    // lane l = m + 16*g holds A[m][k], k = g*16 + j; bit j of abits word = sign
    #pragma unroll
    for (int g = 0; g < 4; ++g)
        abits[(rt*64 + m + 16*g)*10 + t] = bg[g];
    sabs_l[tid] = sabs;
    __syncthreads();
    if (t == 0) {
        float s = 0.f;
        #pragma unroll
        for (int k = 0; k < 9; ++k) s += sabs_l[o*9 + k];
        float sf = s / 576.f;
        consg[o*4 + 0] = sf;
        consg[o*4 + 1] = pr_bias0[o];
        consg[o*4 + 2] = prelu_w[o];
        consg[o*4 + 3] = pr_bias1[o] + skip_b[o];
    }
    if (t == 1) {
        for (int p = 0; p < 2; ++p)
            for (int gg = 0; gg < 4; ++gg)
                for (int i = 0; i < 8; ++i) {
                    float wv = skipw[o*64 + p*32 + gg*8 + i];
                    swfrag[((rt*2 + p)*64 + (m + 16*gg))*8 + i] =
                        __builtin_bit_cast(unsigned short, (__bf16)wv);
                }
    }
}

// ---------------- main kernel: tile 32 px x 4 rows, 256 threads (wave = one row) ------
__global__ __launch_bounds__(256, 4)
void bq_main_kernel(const float* __restrict__ x,        // [8][64][256][256]
                    const float* __restrict__ mb,       // [64]
                    const unsigned short* __restrict__ abits_g,
                    const unsigned short* __restrict__ swfrag,
                    const float* __restrict__ consg,
                    float* __restrict__ out) {
    __shared__ __align__(16) char planes[6*4*34*16];       // 13056 B; first 8 KB double as
                                                           // per-wave bf16 exchange (2 KB/wave)
    __shared__ __align__(16) unsigned short Abits[4*64*10];// 5120 B
    __shared__ __align__(16) float cons[64*4];             // 1024 B  => 19200 B total

    const int tid = threadIdx.x;
    const int l = tid & 63, w = tid >> 6;   // wave w = row w of the 4-row tile
    const int pxg = l & 7,  chg = l >> 3;   // 4-px group / 8-ch group
    const int lg = l >> 4,  lr = l & 15;

    // XCD swizzle: one batch image per XCD (id&7 = XCD under round-robin dispatch);
    // within an XCD consecutive launches walk byp (vertical neighbors -> L2 reuse).
    const int id  = blockIdx.x;                 // 0..4095
    const int vid = (id & 7)*512 + (id >> 3);
    const int byp = vid & 63;                   // 0..63 (4-row strip)
    const int rest = vid >> 6;                  // 0..63
    const int bxp = rest & 7;                   // 0..7
    const int b   = rest >> 3;                  // 0..7

    const int h0 = byp*4 + w, px0 = bxp*32;
    const float* xb = x + (size_t)b * 64 * HW;

    for (int i = tid; i < 1280; i += 256)
        ((unsigned int*)Abits)[i] = ((const unsigned int*)abits_g)[i];
    if (tid < 64) ((f32x4*)cons)[tid] = ((const f32x4*)consg)[tid];

    // ---- Halo sign bits EARLY: 76 px x 2 ch-halves = 152 jobs; results = 2 regs.
    int hr = 0, hc = 0;
    bool hinb = false;
    unsigned int hbb0 = 0, hbb1 = 0;
    if (tid < 152) {
        const int idx = tid >> 1, hh = tid & 1;
        if (idx < 34)      { hr = 0;        hc = idx;      }
        else if (idx < 68) { hr = 5;        hc = idx - 34; }
        else if (idx < 72) { hr = idx - 67; hc = 0;        }   // r = 1..4
        else               { hr = idx - 71; hc = 33;       }   // r = 1..4
        const int hg = byp*4 + hr - 1, wg = px0 + hc - 1;
        hinb = (hg >= 0 && hg < 256 && wg >= 0 && wg < 256);
        if (hinb) {
            const int po = hg*256 + wg;
            #pragma unroll
            for (int j = 0; j < 16; ++j) {
                const int c0 = hh*16 + j;           // p=0 half
                const int c1 = 32 + hh*16 + j;      // p=1 half
                hbb0 |= (__float_as_uint(xb[(size_t)c0*HW + po] + mb[c0]) >> 31) << j;
                hbb1 |= (__float_as_uint(xb[(size_t)c1*HW + po] + mb[c1]) >> 31) << j;
            }
        }
    }

    f32x4 skacc[4][2];
    #pragma unroll
    for (int rt = 0; rt < 4; ++rt)
        #pragma unroll
        for (int g = 0; g < 2; ++g) skacc[rt][g] = (f32x4){0.f, 0.f, 0.f, 0.f};

    // ---- Phase A: wide loads. Lane covers 4 px (pxg*4..+3) x 8 ch (chg*8..+7).
    const f32x4* xrow = (const f32x4*)(xb + (size_t)(chg*8)*HW + h0*256 + px0 + pxg*4);
    f32x4 v[8];
    #pragma unroll
    for (int i = 0; i < 8; ++i) v[i] = xrow[(size_t)i*(HW/4)];
    f32x4 m0 = *(const f32x4*)&mb[chg*8];
    f32x4 m1 = *(const f32x4*)&mb[chg*8 + 4];

    unsigned long long sb0, sb1, sb2, sb3;   // per-px sign words (named: no dyn indexing)
    bf16x8 pk[4];
    {
        unsigned int by[4];
        #pragma unroll
        for (int e = 0; e < 4; ++e) {
            unsigned int bb = 0;
            #pragma unroll
            for (int i = 0; i < 8; ++i) {
                float xv = v[i][e];
                float mm = (i < 4) ? m0[i] : m1[i-4];
                bb |= (__float_as_uint(xv + mm) >> 31) << i;
                pk[e][i] = (__bf16)xv;
            }
            by[e] = bb;
        }
        const int sh = chg*8;
        sb0 = ((unsigned long long)by[0]) << sh;
        sb1 = ((unsigned long long)by[1]) << sh;
        sb2 = ((unsigned long long)by[2]) << sh;
        sb3 = ((unsigned long long)by[3]) << sh;
    }
    // OR-tree over the 8 ch-groups (lane bits 3..5)
    #pragma unroll
    for (int m = 8; m <= 32; m <<= 1) {
        sb0 |= __shfl_xor(sb0, m);
        sb1 |= __shfl_xor(sb1, m);
        sb2 |= __shfl_xor(sb2, m);
        sb3 |= __shfl_xor(sb3, m);
    }

    // ---- Skip-conv MFMAs in two 16-px passes through per-wave LDS exchange.
    // xsl layout: [8 slot][16 px][8] u16 (slot = ch octet); overlays planes.
    unsigned short* xsl = (unsigned short*)((char*)planes + w*2048);
    #pragma unroll
    for (int g = 0; g < 2; ++g) {
        if ((pxg >> 2) == g) {
            const int px16 = (pxg & 3)*4;
            *(bf16x8*)&xsl[(chg*16 + px16 + 0)*8] = pk[0];
            *(bf16x8*)&xsl[(chg*16 + px16 + 1)*8] = pk[1];
            *(bf16x8*)&xsl[(chg*16 + px16 + 2)*8] = pk[2];
            *(bf16x8*)&xsl[(chg*16 + px16 + 3)*8] = pk[3];
        }
        lds_fence();   // wave-synchronous: writes visible before reads
        #pragma unroll
        for (int p = 0; p < 2; ++p) {
            // B-frag: slot p*4 + lg (ch p*32 + lg*8 ..+7), px = lr (actual px g*16+lr)
            bf16x8 bx = *(const bf16x8*)&xsl[((p*4 + lg)*16 + lr)*8];
            #pragma unroll
            for (int rt = 0; rt < 4; ++rt) {
                bf16x8 sa = *(const bf16x8*)&swfrag[((rt*2 + p)*64 + l)*8];
                skacc[rt][g] = __builtin_amdgcn_mfma_f32_16x16x32_bf16(
                    sa, bx, skacc[rt][g], 0, 0, 0);
            }
        }
        lds_fence();   // reads done before next pass overwrites
    }
    __syncthreads();   // all waves done with the exchange overlay

    // ---- Interior sign planes: lane writes px = pxg*4 + (chg&3), 2 slots.
    {
        const int e = chg & 3;
        unsigned long long mysb = (e == 0) ? sb0 : (e == 1) ? sb1 : (e == 2) ? sb2 : sb3;
        const int px = pxg*4 + e;
        const int sbase = (chg >> 2)*2;
        #pragma unroll
        for (int sp = 0; sp < 2; ++sp) {
            const int s = sbase + sp;
            unsigned int slice = (unsigned int)(mysb >> (s*16)) & 0xffffu;
            i32x4 dw;
            dw[0] = expand4(slice & 15);
            dw[1] = expand4((slice >> 4) & 15);
            dw[2] = expand4((slice >> 8) & 15);
            dw[3] = expand4((slice >> 12) & 15);
            *(i32x4*)&planes[(((w + 1)*4 + s)*34 + px + 1)*16] = dw;
        }
    }

    // ---- Halo plane writes (loads already done at kernel top).
    // OOB pixels MUST write zero bytes (exact zero padding), not expand4(0)=+1.
    if (tid < 152) {
        const int hh = tid & 1;
        #pragma unroll
        for (int p = 0; p < 2; ++p) {
            i32x4 dw = (i32x4){0, 0, 0, 0};
            if (hinb) {
                const unsigned int bb = p ? hbb1 : hbb0;
                dw[0] = expand4(bb & 15);
                dw[1] = expand4((bb >> 4) & 15);
                dw[2] = expand4((bb >> 8) & 15);
                dw[3] = expand4((bb >> 12) & 15);
            }
            *(i32x4*)&planes[((hr*4 + (hh + 2*p))*34 + hc)*16] = dw;
        }
    }
    __syncthreads();

    // ---- Phase C: binary conv via i8 MFMA; A expanded from packed bits per tap.
    const int prow_base = ((w*4 + lg)*34 + lr)*16;
    float* outp = out + (size_t)b*64*HW + h0*256 + px0;

    #pragma unroll
    for (int rt = 0; rt < 4; ++rt) {
        // this lane's packed A row: 5 dwords, stride 20 B (bank-conflict-free)
        const unsigned int* arow = (const unsigned int*)&Abits[(rt*64 + l)*10];
        unsigned int ad[5];
        #pragma unroll
        for (int k = 0; k < 5; ++k) ad[k] = arow[k];

        i32x4 bacc0 = (i32x4){0,0,0,0}, bacc1 = (i32x4){0,0,0,0};
        #pragma unroll
        for (int t = 0; t < 9; ++t) {
            const int dr = t / 3, dc = t % 3;
            const unsigned int tb = (ad[t >> 1] >> ((t & 1)*16)) & 0xffffu;
            i32x4 a;
            a[0] = expand4(tb & 15);
            a[1] = expand4((tb >> 4) & 15);
            a[2] = expand4((tb >> 8) & 15);
            a[3] = expand4((tb >> 12) & 15);
            i32x4 b0 = *(const i32x4*)&planes[prow_base + dr*(4*34*16) + dc*16];
            i32x4 b1 = *(const i32x4*)&planes[prow_base + dr*(4*34*16) + dc*16 + 256];
            bacc0 = __builtin_amdgcn_mfma_i32_16x16x64_i8(a, b0, bacc0, 0, 0, 0);
            bacc1 = __builtin_amdgcn_mfma_i32_16x16x64_i8(a, b1, bacc1, 0, 0, 0);
        }
        #pragma unroll
        for (int qi = 0; qi < 4; ++qi) {
            const int o = rt*16 + lg*4 + qi;
            f32x4 c4 = *(const f32x4*)&cons[o*4];   // (sf, pb0, aP, pb1+skip_b)
            {
                float tv = fmaf(c4[0], (float)bacc0[qi], c4[1]);
                tv = fmaxf(tv, 0.f) + c4[2]*fminf(tv, 0.f);
                outp[(size_t)o*HW + lr] = tv + c4[3] + skacc[rt][0][qi];
            }
            {
                float tv = fmaf(c4[0], (float)bacc1[qi], c4[1]);
                tv = fmaxf(tv, 0.f) + c4[2]*fminf(tv, 0.f);
                outp[(size_t)o*HW + 16 + lr] = tv + c4[3] + skacc[rt][1][qi];
            }
        }
    }
}

extern "C" void kernel_launch(void* const* d_in, const int* in_sizes, int n_in,
                              void* d_out, int out_size, void* d_ws, size_t ws_size,
                              hipStream_t stream) {
    const float* x      = (const float*)d_in[0];
    const float* mb     = (const float*)d_in[1];
    const float* weight = (const float*)d_in[2];
    const float* pb0    = (const float*)d_in[3];
    const float* pw     = (const float*)d_in[4];
    const float* pb1    = (const float*)d_in[5];
    const float* skw    = (const float*)d_in[6];
    const float* skb    = (const float*)d_in[7];
    float* out = (float*)d_out;

    char* ws = (char*)d_ws;
    unsigned short* abits  = (unsigned short*)ws;              // 5120 B
    unsigned short* swfrag = (unsigned short*)(ws + 5120);     // 8192 B
    float*          consg  = (float*)(ws + 13312);             // 1024 B (total 14336)

    hipLaunchKernelGGL(bq_prep_kernel, dim3(1), dim3(576), 0, stream,
                       weight, pb0, pw, pb1, skb, skw, abits, swfrag, consg);
    hipLaunchKernelGGL(bq_main_kernel, dim3(4096), dim3(256), 0, stream,
                       x, mb, abits, swfrag, consg, out);
}